// Round 4
// baseline (350.345 us; speedup 1.0000x reference)
//
#include <hip/hip_runtime.h>
#include <cstdint>
#include <cstddef>

#define BB   4
#define AA   256
#define NNB  64
#define FF   128
#define NBAS 20
#define NLAY 3
#define BA   (BB*AA)        // 1024 atoms total
#define EDG  (BA*NNB)       // 65536 edges

typedef __attribute__((ext_vector_type(8))) short bf16x8;
typedef __attribute__((ext_vector_type(4))) float f32x4;

__device__ __forceinline__ float silu_f(float x){ return x / (1.0f + __expf(-x)); }

// round-to-nearest-even f32 -> bf16 bits
__device__ __forceinline__ unsigned short f2bf(float x){
  unsigned int u = __float_as_uint(x);
  u += 0x7FFFu + ((u >> 16) & 1u);
  return (unsigned short)(u >> 16);
}
__device__ __forceinline__ unsigned int pk2(float a, float b){
  return (unsigned int)f2bf(a) | ((unsigned int)f2bf(b) << 16);
}

// ---------------- init: inv_node = emb[atomic_numbers] ----------------
__global__ void k_init(const int* __restrict__ z, const float* __restrict__ emb,
                       float* __restrict__ inv_node){
  int id = blockIdx.x*256 + threadIdx.x;
  int atom = id >> 7, o = id & 127;
  inv_node[id] = emb[z[atom]*FF + o];
}

// ---------------- geometry: bf16 rbf [EDG][32] (zero-padded), cutoff, unit ----------------
__global__ void k_geom(const float* __restrict__ dist, const float* __restrict__ dvec,
                       unsigned short* __restrict__ rbf_bf, float* __restrict__ cutw,
                       float* __restrict__ unitv){
  int e = blockIdx.x*256 + threadIdx.x;
  float d = dist[e];
  float x = d * 0.2f;
  float x2 = x*x, x4 = x2*x2, x6 = x4*x2, x7 = x6*x, x8 = x7*x;
  float f = 1.0f - 28.0f*x6 + 48.0f*x7 - 21.0f*x8;
  f = (x < 1.0f) ? f : 0.0f;
  cutw[e] = f;
  float inv = 1.0f/(d + 1e-8f);
  unitv[(size_t)e*3+0] = dvec[(size_t)e*3+0]*inv;
  unitv[(size_t)e*3+1] = dvec[(size_t)e*3+1]*inv;
  unitv[(size_t)e*3+2] = dvec[(size_t)e*3+2]*inv;
  const float c = 0.6283185307179586f;        // pi/5
  unsigned short* rb = rbf_bf + (size_t)e*32;
  #pragma unroll
  for (int n=1;n<=NBAS;++n) rb[n-1] = f2bf(sinf((float)n*c*d)*inv);
  #pragma unroll
  for (int k=NBAS;k<32;++k) rb[k] = 0;
}

// ------------- weight conversion: eqf_W1, eqf_W2, eme_W1, eme_W2 (+ padded me_W) ------------
__global__ void k_cvtw(const float* __restrict__ a, const float* __restrict__ b,
                       const float* __restrict__ c, const float* __restrict__ d,
                       const float* __restrict__ me, unsigned short* __restrict__ out){
  int id = blockIdx.x*256 + threadIdx.x;
  if (id < 196608){
    int reg = id / 49152, off = id - reg*49152;
    const float* src = (reg==0)?a:(reg==1)?b:(reg==2)?c:d;
    out[id] = f2bf(src[off]);
  } else if (id < 196608 + 12288){
    int p = id - 196608;
    int l = p >> 12;            // layer
    int rem = p & 4095;
    int row = rem >> 5, k = rem & 31;
    float v = (k < NBAS) ? me[((size_t)l*FF + row)*NBAS + k] : 0.0f;
    out[id] = f2bf(v);
  }
}

// ---------------- f32 two-pass MLP core over 16 rows (node MLPs) ----------------
__device__ __forceinline__ void mlp16(const float (*xs)[FF], float (*hs)[FF], int o,
    const float* __restrict__ W1, const float* __restrict__ b1,
    const float* __restrict__ W2, const float* __restrict__ b2, float acc[16]){
  #pragma unroll
  for (int r=0;r<16;++r) acc[r] = b1[o];
  #pragma unroll
  for (int ic=0;ic<4;++ic){
    float4 wv[8];
    #pragma unroll
    for (int j=0;j<8;++j) wv[j] = *reinterpret_cast<const float4*>(&W1[(size_t)o*FF + ic*32 + j*4]);
    #pragma unroll
    for (int r=0;r<16;++r){
      #pragma unroll
      for (int j=0;j<8;++j){
        float4 xv = *reinterpret_cast<const float4*>(&xs[r][ic*32+j*4]);
        acc[r] = fmaf(xv.x, wv[j].x, acc[r]);
        acc[r] = fmaf(xv.y, wv[j].y, acc[r]);
        acc[r] = fmaf(xv.z, wv[j].z, acc[r]);
        acc[r] = fmaf(xv.w, wv[j].w, acc[r]);
      }
    }
  }
  #pragma unroll
  for (int r=0;r<16;++r) hs[r][o] = silu_f(acc[r]);
  __syncthreads();
  #pragma unroll
  for (int r=0;r<16;++r) acc[r] = b2[o];
  #pragma unroll
  for (int ic=0;ic<4;++ic){
    float4 wv[8];
    #pragma unroll
    for (int j=0;j<8;++j) wv[j] = *reinterpret_cast<const float4*>(&W2[(size_t)o*FF + ic*32 + j*4]);
    #pragma unroll
    for (int r=0;r<16;++r){
      #pragma unroll
      for (int j=0;j<8;++j){
        float4 xv = *reinterpret_cast<const float4*>(&hs[r][ic*32+j*4]);
        acc[r] = fmaf(xv.x, wv[j].x, acc[r]);
        acc[r] = fmaf(xv.y, wv[j].y, acc[r]);
        acc[r] = fmaf(xv.z, wv[j].z, acc[r]);
        acc[r] = fmaf(xv.w, wv[j].w, acc[r]);
      }
    }
  }
}

// ---------------- three node MLPs in one dispatch (blockIdx.y selects) ----------------
__global__ __launch_bounds__(128) void k_mlp_node3(const float* __restrict__ X,
    const float* W1a, const float* b1a, const float* W2a, const float* b2a, float* Ya,
    const float* W1b, const float* b1b, const float* W2b, const float* b2b, float* Yb,
    const float* W1c, const float* b1c, const float* W2c, const float* b2c, float* Yc){
  const float *W1,*b1,*W2,*b2; float* Y;
  if (blockIdx.y==0){ W1=W1a;b1=b1a;W2=W2a;b2=b2a;Y=Ya; }
  else if (blockIdx.y==1){ W1=W1b;b1=b1b;W2=W2b;b2=b2b;Y=Yb; }
  else { W1=W1c;b1=b1c;W2=W2c;b2=b2c;Y=Yc; }
  __shared__ __align__(16) float xs[16][FF];
  __shared__ __align__(16) float hs[16][FF];
  const int o = threadIdx.x;
  const int row0 = blockIdx.x * 16;
  #pragma unroll
  for (int r=0;r<16;++r) xs[r][o] = X[(size_t)(row0+r)*FF + o];
  __syncthreads();
  float acc[16];
  mlp16(xs, hs, o, W1, b1, W2, b2, acc);
  #pragma unroll
  for (int r=0;r<16;++r) Y[(size_t)(row0+r)*FF + o] = acc[r];
}

// =====================================================================
// Stage kernel: one block = one atom. me-MLP via MFMA (swapped), build
// inv_msg (bf16 -> global, coalesced via LDS), eqmsgF/mask -> scalg,
// eq_F accumulation.
// =====================================================================
__global__ __launch_bounds__(256) void k_stage(
    const unsigned short* __restrict__ rbf_bf,
    const float* __restrict__ cutw, const float* __restrict__ unitv,
    const float* __restrict__ maskp, const int* __restrict__ nbrs,
    const float* __restrict__ msg_node,
    const unsigned short* __restrict__ meWb, const float* __restrict__ meb,
    const float* __restrict__ eqcW,
    unsigned short* __restrict__ inv_msg, float* __restrict__ scalg,
    float* __restrict__ eqF){
  __shared__ unsigned short Hs[64*136];
  __shared__ float eqFred[4][3];
  const int t = threadIdx.x, w = t>>6, l = t&63;
  const int atom = blockIdx.x;
  const int bbase = (atom/AA)*AA;
  const int le = w*16 + (l&15);
  const int eg = atom*NNB + le;
  const int kg = (l>>4)<<3;
  const int r0 = (l>>4)<<2;

  f32x4 acc[8];
  bf16x8 rfr = *(const bf16x8*)(rbf_bf + (size_t)eg*32 + kg);
  #pragma unroll
  for (int nt=0;nt<8;++nt){
    bf16x8 wfr = *(const bf16x8*)(meWb + (nt*16 + (l&15))*32 + kg);
    acc[nt] = __builtin_amdgcn_mfma_f32_16x16x32_bf16(wfr, rfr, f32x4{0.f,0.f,0.f,0.f}, 0,0,0);
  }
  const float ct = cutw[eg];
  const int   nbv = bbase + nbrs[eg];
  float pv = 0.f;
  #pragma unroll
  for (int nt=0;nt<8;++nt){
    int o0 = nt*16 + r0;
    float4 mb = *(const float4*)(meb + o0);
    float4 mi = *(const float4*)(msg_node + (size_t)atom*FF + o0);
    float4 mf = *(const float4*)(msg_node + (size_t)nbv*FF + o0);
    float4 ec = *(const float4*)(eqcW + o0);
    float v0 = (acc[nt][0]+mb.x)*ct*mi.x*mf.x;
    float v1 = (acc[nt][1]+mb.y)*ct*mi.y*mf.y;
    float v2 = (acc[nt][2]+mb.z)*ct*mi.z*mf.z;
    float v3 = (acc[nt][3]+mb.w)*ct*mi.w*mf.w;
    pv = fmaf(v0,ec.x, fmaf(v1,ec.y, fmaf(v2,ec.z, fmaf(v3,ec.w, pv))));
    uint2 u; u.x = pk2(v0,v1); u.y = pk2(v2,v3);
    *(uint2*)(&Hs[le*136 + o0]) = u;
  }
  pv += __shfl_xor(pv,16); pv += __shfl_xor(pv,32);
  float cf0=0.f, cf1=0.f, cf2=0.f;
  if (l < 16){
    float m  = maskp[eg];                    // own edge's mask (no LDS race)
    float s0 = pv*unitv[(size_t)eg*3+0];
    float s1 = pv*unitv[(size_t)eg*3+1];
    float s2 = pv*unitv[(size_t)eg*3+2];
    float4 sv; sv.x=s0; sv.y=s1; sv.z=s2; sv.w=m;
    *(float4*)(scalg + (size_t)eg*4) = sv;
    cf0 = s0*m; cf1 = s1*m; cf2 = s2*m;
  }
  #pragma unroll
  for (int s2=1; s2<16; s2<<=1){
    cf0 += __shfl_xor(cf0,s2); cf1 += __shfl_xor(cf1,s2); cf2 += __shfl_xor(cf2,s2);
  }
  if (l == 0){ eqFred[w][0]=cf0; eqFred[w][1]=cf1; eqFred[w][2]=cf2; }
  __syncthreads();
  // coalesced LDS -> global copy of inv_msg (bf16)
  unsigned short* og = inv_msg + (size_t)atom*NNB*FF;
  #pragma unroll
  for (int c=t; c<1024; c+=256){
    int row = c >> 4, ko = (c & 15) << 3;
    *(int4*)(og + row*FF + ko) = *(const int4*)(&Hs[row*136 + ko]);
  }
  if (t < 3) eqF[atom*3+t] += eqFred[0][t]+eqFred[1][t]+eqFred[2][t]+eqFred[3][t];
}

// =====================================================================
// Pair kernel: grid (BA, 2). y=0: eqf MLP + masked eqmsgF reduce.
//              y=1: eme MLP + eqdr-neighbor-gather reduce.
// GEMM1 swapped -> Hs (packed uint2) -> GEMM2 unswapped -> reduce.
// =====================================================================
__global__ __launch_bounds__(256) void k_pair(
    const unsigned short* __restrict__ inv_msg,
    const unsigned short* __restrict__ W1eq, const float* __restrict__ b1eq,
    const unsigned short* __restrict__ W2eq, const float* __restrict__ b2eq,
    const unsigned short* __restrict__ W1me, const unsigned short* __restrict__ W2me,
    const float* __restrict__ scalg, const float* __restrict__ maskp,
    const int* __restrict__ nbrs, const float* __restrict__ eqdr,
    float* __restrict__ eqf_out, float* __restrict__ updf,
    float* __restrict__ upddr){
  __shared__ unsigned short Hs[64*136];
  __shared__ float scal[64][4];
  __shared__ int   nbq[64];
  __shared__ float afl[4][384];
  const int t = threadIdx.x, w = t>>6, l = t&63;
  const int atom = blockIdx.x;
  const bool is_eqf = (blockIdx.y == 0);
  const int le = w*16 + (l&15);
  const int kg = (l>>4)<<3;
  const int r0 = (l>>4)<<2;

  if (is_eqf){
    if (t < 64){
      float4 s = *(const float4*)(scalg + (size_t)(atom*NNB + t)*4);
      scal[t][0]=s.x; scal[t][1]=s.y; scal[t][2]=s.z; scal[t][3]=s.w;
    }
  } else {
    if (t < 64){
      int e2 = atom*NNB + t;
      nbq[t]     = (atom/AA)*AA + nbrs[e2];
      scal[t][3] = maskp[e2];
    }
  }

  // X fragments from global inv_msg
  bf16x8 xfrag[4];
  #pragma unroll
  for (int ks=0;ks<4;++ks)
    xfrag[ks] = *(const bf16x8*)(inv_msg + ((size_t)atom*NNB + le)*FF + ks*32 + kg);

  const unsigned short* W1 = is_eqf ? W1eq : W1me;
  const unsigned short* W2 = is_eqf ? W2eq : W2me;

  // ---------------- GEMM1 (swapped) -> Hs ----------------
  f32x4 acc[8];
  #pragma unroll
  for (int nt=0;nt<8;++nt) acc[nt] = f32x4{0.f,0.f,0.f,0.f};
  #pragma unroll
  for (int nt=0;nt<8;++nt)
    #pragma unroll
    for (int ks=0;ks<4;++ks){
      bf16x8 wfr = *(const bf16x8*)(W1 + (nt*16+(l&15))*FF + ks*32 + kg);
      acc[nt] = __builtin_amdgcn_mfma_f32_16x16x32_bf16(wfr, xfrag[ks], acc[nt], 0,0,0);
    }
  #pragma unroll
  for (int nt=0;nt<8;++nt){
    int o0 = nt*16 + r0;
    float4 bb = is_eqf ? *(const float4*)(b1eq + o0) : float4{0.f,0.f,0.f,0.f};
    uint2 u;
    u.x = pk2(silu_f(acc[nt][0]+bb.x), silu_f(acc[nt][1]+bb.y));
    u.y = pk2(silu_f(acc[nt][2]+bb.z), silu_f(acc[nt][3]+bb.w));
    *(uint2*)(&Hs[le*136 + o0]) = u;
  }
  __syncthreads();

  // ---------------- GEMM2 (unswapped) + reduce ----------------
  bf16x8 hfr[4];
  #pragma unroll
  for (int ks=0;ks<4;++ks)
    hfr[ks] = *(const bf16x8*)(Hs + le*136 + ks*32 + kg);
  #pragma unroll
  for (int nt=0;nt<8;++nt) acc[nt] = f32x4{0.f,0.f,0.f,0.f};
  #pragma unroll
  for (int nt=0;nt<8;++nt)
    #pragma unroll
    for (int ks=0;ks<4;++ks){
      bf16x8 wfr = *(const bf16x8*)(W2 + (nt*16+(l&15))*FF + ks*32 + kg);
      acc[nt] = __builtin_amdgcn_mfma_f32_16x16x32_bf16(hfr[ks], wfr, acc[nt], 0,0,0);
    }
  if (is_eqf){
    #pragma unroll
    for (int nt=0;nt<8;++nt){
      int col = nt*16 + (l&15);
      float bb = b2eq[col];
      float q0=0.f,q1=0.f,q2=0.f;
      #pragma unroll
      for (int r=0;r<4;++r){
        int row = w*16 + r0 + r;
        float ym = (acc[nt][r] + bb) * scal[row][3];
        q0 = fmaf(ym, scal[row][0], q0);
        q1 = fmaf(ym, scal[row][1], q1);
        q2 = fmaf(ym, scal[row][2], q2);
      }
      q0 += __shfl_xor(q0,16); q0 += __shfl_xor(q0,32);
      q1 += __shfl_xor(q1,16); q1 += __shfl_xor(q1,32);
      q2 += __shfl_xor(q2,16); q2 += __shfl_xor(q2,32);
      if (l < 16){
        afl[w][0*128+col] = q0; afl[w][1*128+col] = q1; afl[w][2*128+col] = q2;
      }
    }
  } else {
    #pragma unroll
    for (int nt=0;nt<8;++nt){
      int col = nt*16 + (l&15);
      float q0=0.f,q1=0.f,q2=0.f;
      #pragma unroll
      for (int r=0;r<4;++r){
        int row = w*16 + r0 + r;
        float ym = acc[nt][r] * scal[row][3];
        const float* gd = eqdr + (size_t)nbq[row]*384 + col;
        q0 = fmaf(ym, gd[0],   q0);
        q1 = fmaf(ym, gd[128], q1);
        q2 = fmaf(ym, gd[256], q2);
      }
      q0 += __shfl_xor(q0,16); q0 += __shfl_xor(q0,32);
      q1 += __shfl_xor(q1,16); q1 += __shfl_xor(q1,32);
      q2 += __shfl_xor(q2,16); q2 += __shfl_xor(q2,32);
      if (l < 16){
        afl[w][0*128+col] = q0; afl[w][1*128+col] = q1; afl[w][2*128+col] = q2;
      }
    }
  }
  __syncthreads();
  if (is_eqf){
    for (int i=t; i<384; i+=256){
      float s = afl[0][i]+afl[1][i]+afl[2][i]+afl[3][i];
      size_t o = (size_t)atom*384 + i;
      updf[o] = s;
      eqf_out[o] += s;
    }
  } else {
    for (int i=t; i<384; i+=256){
      upddr[(size_t)atom*384 + i] = afl[0][i]+afl[1][i]+afl[2][i]+afl[3][i];
    }
  }
}

// ---------------- finalize: eq_dr update + inv_node update ----------------
__global__ void k_fin(const float* __restrict__ esu, const float* __restrict__ isu,
                      const float* __restrict__ updf, const float* __restrict__ upddr,
                      const float* __restrict__ eqf, float* __restrict__ eqdr,
                      float* __restrict__ inv_node){
  int id = blockIdx.x*256+threadIdx.x;
  int atom = id >> 7, o = id & 127;
  float es = esu[id];
  float sum = 0.f;
  size_t b0 = (size_t)atom*3*FF + o;
  #pragma unroll
  for (int c=0;c<3;++c){
    size_t k = b0 + (size_t)c*FF;
    float nd = eqdr[k] + upddr[k] + es*updf[k];
    eqdr[k] = nd;
    sum = fmaf(eqf[k], nd, sum);
  }
  inv_node[id] = fmaf(-isu[id], sum, inv_node[id]);
}

extern "C" void kernel_launch(void* const* d_in, const int* in_sizes, int n_in,
                              void* d_out, int out_size, void* d_ws, size_t ws_size,
                              hipStream_t stream){
  const int*   z     = (const int*)  d_in[0];
  const int*   nbrs  = (const int*)  d_in[2];
  const float* maskp = (const float*)d_in[3];
  const float* dist  = (const float*)d_in[4];
  const float* dvec  = (const float*)d_in[5];
  const float* emb   = (const float*)d_in[6];
  const float* me_W  = (const float*)d_in[7];
  const float* me_b  = (const float*)d_in[8];
  const float* mn_W1 = (const float*)d_in[9];
  const float* mn_b1 = (const float*)d_in[10];
  const float* mn_W2 = (const float*)d_in[11];
  const float* mn_b2 = (const float*)d_in[12];
  const float* eqc_W = (const float*)d_in[13];
  const float* eqf_W1= (const float*)d_in[14];
  const float* eqf_b1= (const float*)d_in[15];
  const float* eqf_W2= (const float*)d_in[16];
  const float* eqf_b2= (const float*)d_in[17];
  const float* esu_W1= (const float*)d_in[18];
  const float* esu_b1= (const float*)d_in[19];
  const float* esu_W2= (const float*)d_in[20];
  const float* esu_b2= (const float*)d_in[21];
  const float* eme_W1= (const float*)d_in[22];
  const float* eme_W2= (const float*)d_in[23];
  const float* isu_W1= (const float*)d_in[24];
  const float* isu_b1= (const float*)d_in[25];
  const float* isu_W2= (const float*)d_in[26];
  const float* isu_b2= (const float*)d_in[27];

  float* out      = (float*)d_out;
  float* inv_node = out;                        // BA*FF   = 131072
  float* eqF      = out + 131072;               // BA*3    = 3072
  float* eqf      = out + 134144;               // BA*3*FF = 393216
  float* eqdr     = out + 527360;               // BA*3*FF = 393216

  // workspace layout (floats)
  float* w        = (float*)d_ws;
  float* cutw     = w;                          //    65,536
  float* unitv    = w + 65536;                  //   196,608
  float* msg_node = w + 262144;                 //   131,072
  float* esu_o    = w + 393216;                 //   131,072
  float* isu_o    = w + 524288;                 //   131,072
  float* updf     = w + 655360;                 //   393,216
  float* upddr    = w + 1048576;                //   393,216
  float* scalg    = w + 1441792;                //   262,144 (EDG*4)
  unsigned short* rbf_bf  = (unsigned short*)(w + 1703936); // EDG*32 us = 1,048,576 f
  unsigned short* wbf     = (unsigned short*)(w + 2752512); // 208,896 us = 104,448 f
  unsigned short* inv_msg = (unsigned short*)(w + 2856960); // EDG*FF us = 4,194,304 f

  hipMemsetAsync(out + 131072, 0, (size_t)(3072 + 2*393216)*sizeof(float), stream);

  k_cvtw<<<817, 256, 0, stream>>>(eqf_W1, eqf_W2, eme_W1, eme_W2, me_W, wbf);
  k_init<<<BA*FF/256, 256, 0, stream>>>(z, emb, inv_node);
  k_geom<<<EDG/256,   256, 0, stream>>>(dist, dvec, rbf_bf, cutw, unitv);

  for (int l=0; l<NLAY; ++l){
    size_t oW = (size_t)l*FF*FF, oB = (size_t)l*FF;
    const unsigned short* eqfW1b = wbf + 0*49152 + l*16384;
    const unsigned short* eqfW2b = wbf + 1*49152 + l*16384;
    const unsigned short* emeW1b = wbf + 2*49152 + l*16384;
    const unsigned short* emeW2b = wbf + 3*49152 + l*16384;
    const unsigned short* meWb   = wbf + 196608  + l*4096;

    k_mlp_node3<<<dim3(BA/16, 3), 128, 0, stream>>>(inv_node,
        mn_W1+oW,  mn_b1+oB,  mn_W2+oW,  mn_b2+oB,  msg_node,
        esu_W1+oW, esu_b1+oB, esu_W2+oW, esu_b2+oB, esu_o,
        isu_W1+oW, isu_b1+oB, isu_W2+oW, isu_b2+oB, isu_o);
    k_stage<<<BA, 256, 0, stream>>>(rbf_bf, cutw, unitv, maskp, nbrs, msg_node,
        meWb, me_b+oB, eqc_W+oB, inv_msg, scalg, eqF);
    k_pair<<<dim3(BA, 2), 256, 0, stream>>>(inv_msg,
        eqfW1b, eqf_b1+oB, eqfW2b, eqf_b2+oB, emeW1b, emeW2b,
        scalg, maskp, nbrs, eqdr, eqf, updf, upddr);
    k_fin<<<BA*FF/256, 256, 0, stream>>>(esu_o, isu_o, updf, upddr, eqf, eqdr, inv_node);
  }
}